// Round 6
// baseline (1889.898 us; speedup 1.0000x reference)
//
#include <hip/hip_runtime.h>
#include <math.h>

// Problem: MPMatcher  S=6, B=16, L=8, M=256, K=128
// Phase 1 (PASSING, DO NOT TOUCH): cost f32, ocml logf, *(1/6) reciprocal mean.
// Phase 2: reference's buggy greedy walk, f64-exact. R17 = R15 (best: 1297us)
// + SAFE counter instrumentation (R16's dangling asm ds_read clobbered a
// reallocated VGPR -> absmax 35; lesson: compiler-managed volatile reads only):
//   - MARCH steps (dummy wins): volatile LDS read, 64 lanes stride 512B -> all
//     bank 0, 64-way conflict, compiler emits ds_read + s_waitcnt (safe).
//     marches = (SQ_LDS_BANK_CONFLICT - 33357) / ~62; adds known ~64cy/march.
//   - REAL-WIN steps (incl. walk-ending breaks): lane0 writes one unique 64B
//     line into this block's own DEAD cost region (already staged to LDS).
//     realwins = (WRITE_SIZE_KB - 8) * 16. Count/block ~130-500 << 2048 mask.
//   - iters = m + r; true cy/iter = dur*2400*16/(m+r) - 62*m/(m+r).
// R15 core (unchanged, passing): fully-deferred dual updates, software-
// pipelined row load, value-DPP ladder + ballot extraction, rows 1..128
// pre-matched, dummies never re-matched (i0n = j1-128 statically).

#define S_ 6
#define B_ 16
#define L_ 8
#define M_ 256
#define K_ 128

// ---------------------------------------------------------------- cost kernel
__global__ void cost_kernel(const float* __restrict__ mp,   // (6,16,8,256,2)
                            const float* __restrict__ mv,   // (6,16,256,1)
                            const float* __restrict__ gt,   // (6,16,128,2)
                            const float* __restrict__ gv,   // (6,16,128,1)
                            float* __restrict__ cost)       // (16,256,128)
{
#pragma clang fp contract(off)
    const int b = blockIdx.x;
    const int m = blockIdx.y;
    const int k = threadIdx.x;

    float accS = 0.0f;
    for (int s = 0; s < S_; ++s) {
        const int sb = s * B_ + b;
        const float gx = gt[(sb * K_ + k) * 2 + 0];
        const float gy = gt[(sb * K_ + k) * 2 + 1];
        float accL = 0.0f;
#pragma unroll
        for (int l = 0; l < L_; ++l) {
            const int base = ((sb * L_ + l) * M_ + m) * 2;
            const float dx = fabsf(mp[base + 0] - gx);
            const float dy = fabsf(mp[base + 1] - gy);
            const float diff = dx + dy;
            const float dl = (float)(L_ - (l + 1)) * 0.05f;
            const float t = diff - dl;
            accL += fmaxf(t, 0.0f);
        }
        const float meanL = accL * 0.125f;
        const float mvv = mv[sb * M_ + m];
        const float gtv = gv[sb * K_ + k];
        const float lp = -logf(mvv);
        const float ln = -logf(1.0f - mvv);
        const float val = (gtv != 0.0f) ? (5.0f * meanL + lp) : ln;
        accS += val;
    }
    cost[(b * M_ + m) * K_ + k] = accS * (1.0f / 6.0f);
}

// --------------------------------------------------------------- bit helpers
__device__ __forceinline__ double bits2d(int lo, int hi) {
    const unsigned long long u =
        ((unsigned long long)(unsigned)hi << 32) | (unsigned)lo;
    return __longlong_as_double((long long)u);
}
__device__ __forceinline__ void d2bits(double d, int& lo, int& hi) {
    const unsigned long long u = (unsigned long long)__double_as_longlong(d);
    lo = (int)(u & 0xffffffffull);
    hi = (int)(u >> 32);
}

// ------------------------------------------------------------- matcher kernel
// One wave per batch. Lane owns real cols j=2*lane+1, 2*lane+2 (slots 0,1)
// and dummy cols j=2*lane+129, 2*lane+130 (slots 2,3).
__global__ __launch_bounds__(64, 1) void match_kernel(const float* __restrict__ cost,
                                                      int* __restrict__ out)
{
#pragma clang fp contract(off)
    const int b = blockIdx.x;
    const int lane = threadIdx.x;   // 0..63
    const float* C = cost + (size_t)b * M_ * K_;
    volatile float* Cw = (volatile float*)(cost + (size_t)b * M_ * K_);
    const double INF = __builtin_inf();
    const int BIG = 0x7fffffff;

    __shared__ float  C_lds[M_ * K_];   // 128 KB cost slab (row-major, = global)
    __shared__ double u_lds[257];       // u[0..256], 1-based rows
    __shared__ int    p_lds[257];       // p[j] = row matched to col j; 0 = free

    // stage the batch's cost slab into LDS (coalesced float4 copies)
    for (int t = lane; t < (M_ * K_) / 4; t += 64)
        ((float4*)C_lds)[t] = ((const float4*)C)[t];

    // rows 1..128 pre-matched to dummy cols 129..256 (exact, proven R8)
    for (int t = lane; t < 257; t += 64) {
        u_lds[t] = 0.0;
        p_lds[t] = (t >= 129) ? (t - 128) : 0;
    }
    __syncthreads();

    double v0 = 0.0, v1 = 0.0, v2 = 0.0, v3 = 0.0;  // column potentials
    int rw = 0;    // real-win counter (wave-uniform), WRITE_SIZE channel

    for (int i = 129; i <= 256; ++i) {
        // ---- row start: snapshot caches. p static during walk; dummies never
        // re-matched (p[dummy j] = j-128 statically); u[p[j]] for free cols
        // never updated mid-walk -> snapshots valid for broadcasts.
        const int pj0 = p_lds[2 * lane + 1];
        const int pj1 = p_lds[2 * lane + 2];
        const double up0 = u_lds[pj0], up1 = u_lds[pj1];
        const double up2 = u_lds[2 * lane + 1];   // p[2*lane+129] = 2*lane+1
        const double up3 = u_lds[2 * lane + 2];   // p[2*lane+130] = 2*lane+2

        float2 cc = *(const float2*)(C_lds + (i - 1) * K_ + 2 * lane);
        double u_i0 = 0.0;
        int used = 0;
        int j1 = 0;
        double usum = 0.0;
        // usum snapshot at choice time for each owned slot (valid iff used bit)
        double Ua0 = 0.0, Ua1 = 0.0, Ua2 = 0.0, Ua3 = 0.0;

        for (;;) {
            // candidates: cur = (cost - u[i0]) - v   (exact ref op order, f64)
            double cd0 = ((double)cc.x - u_i0) - v0;
            double cd1 = ((double)cc.y - u_i0) - v1;
            double cd2 = (0.0 - u_i0) - v2;
            double cd3 = (0.0 - u_i0) - v3;
            if (used & 1) cd0 = INF;
            if (used & 2) cd1 = INF;
            if (used & 4) cd2 = INF;
            if (used & 8) cd3 = INF;

            // local value min (+-0 ambiguity harmless, proven R9/R10)
            const double m01 = fmin(cd0, cd1);
            const double m23 = fmin(cd2, cd3);
            double bv = fmin(m01, m23);

            // wave value-min via DPP ladder (VALU pipe), result in lane 63
            int lo, hi; d2bits(bv, lo, hi);
#define MIN_STAGE(CTRL, RM)                                                      \
            {                                                                    \
                const int nlo = __builtin_amdgcn_update_dpp(lo, lo, CTRL, RM, 0xf, false); \
                const int nhi = __builtin_amdgcn_update_dpp(hi, hi, CTRL, RM, 0xf, false); \
                const double mv2 = fmin(bits2d(lo, hi), bits2d(nlo, nhi));       \
                d2bits(mv2, lo, hi);                                             \
            }
            MIN_STAGE(0x111, 0xf)   // row_shr:1
            MIN_STAGE(0x112, 0xf)   // row_shr:2
            MIN_STAGE(0x114, 0xf)   // row_shr:4
            MIN_STAGE(0x118, 0xf)   // row_shr:8
            MIN_STAGE(0x142, 0xa)   // row_bcast:15 -> rows 1,3
            MIN_STAGE(0x143, 0xc)   // row_bcast:31 -> rows 2,3
#undef MIN_STAGE
            const int mlo = __builtin_amdgcn_readlane(lo, 63);
            const int mhi = __builtin_amdgcn_readlane(hi, 63);
            const double delta = bits2d(mlo, mhi);   // == min value (scalar)

            // first-index extraction: cd == delta marks min-achievers; lane
            // order == j order within each class; real js (<=128) < dummy js
            int jr = BIG;
            if (cd1 == delta) jr = 2 * lane + 2;
            if (cd0 == delta) jr = 2 * lane + 1;
            int jd = BIG;
            if (cd3 == delta) jd = 2 * lane + 130;
            if (cd2 == delta) jd = 2 * lane + 129;
            const unsigned long long br = __ballot(jr != BIG);
            const unsigned long long bd = __ballot(jd != BIG);
            const unsigned long long bb = br ? br : bd;
            const int cand = (br != 0ull) ? jr : jd;
            j1 = __builtin_amdgcn_readlane(cand, (int)__builtin_ctzll(bb));

            // next row: dummies are never re-matched -> p[j1] = j1-128 statically
            int ol, sl;
            if (j1 >= 129) { ol = (j1 - 129) >> 1; sl = 2 + ((j1 - 129) & 1); }
            else           { ol = (j1 - 1) >> 1;   sl = (j1 - 1) & 1; }
            const int psel = (sl == 0) ? pj0 : (sl == 1) ? pj1 : 0;
            const int i0n = (j1 >= 129) ? (j1 - 128)
                                        : __builtin_amdgcn_readlane(psel, ol);

            // speculative next-row load, issued ASAP (clamped; unused on break)
            const int rown = (i0n > 0 ? i0n : 1) - 1;
            const float2 ccn = *(const float2*)(C_lds + rown * K_ + 2 * lane);

            // ---- instrumentation channels (compiler-managed, safe) ----
            if (j1 >= 129) {
                // MARCH: volatile LDS read, 64 lanes stride 512B -> all bank 0
                // (64-way conflict, ~62 extra conflict-cycles per event);
                // compiler inserts the s_waitcnt before use -> no clobber
                const int dmy = *(volatile int*)((volatile char*)C_lds + (lane << 9));
                asm volatile("" :: "v"(dmy));
            } else {
                // REAL WIN: one unique 64B line into dead staged cost region
                if (lane == 0) Cw[(rw & 2047) * 16] = 1.0f;
                ++rw;
            }

            // ---- shadow work (under the load's latency) ----
            // duals deferred to commit (R15, proven); running delta-sum only
            usum += delta;

            // u[p[j1]] broadcast from owner's row-start snapshot
            const double usel = (sl == 0) ? up0 : (sl == 1) ? up1
                              : (sl == 2) ? up2 : up3;
            int ulo, uhi; d2bits(usel, ulo, uhi);
            const double u_n = bits2d(__builtin_amdgcn_readlane(ulo, ol),
                                      __builtin_amdgcn_readlane(uhi, ol));

            if (i0n == 0) break;    // free real column -> augment (way==0)

            // mark j1 used (it is j0 of the next iteration, ref marks at top)
            // and snapshot the running sum for the deferred update
            if (lane == ol) {
                used |= (1 << sl);
                if (sl == 0)      Ua0 = usum;
                else if (sl == 1) Ua1 = usum;
                else if (sl == 2) Ua2 = usum;
                else              Ua3 = usum;
            }
            u_i0 = u_n;
            cc = ccn;
        }

        // ---- commit: deferred dual updates. Column j chosen at snapshot U_j
        // accumulates amt = usum_final - U_j (== sum of all later deltas).
        // Distinct columns -> distinct rows -> no LDS write conflicts.
        __syncthreads();
        if (used & 1) { const double a = usum - Ua0; u_lds[pj0] = up0 + a; v0 -= a; }
        if (used & 2) { const double a = usum - Ua1; u_lds[pj1] = up1 + a; v1 -= a; }
        if (used & 4) { const double a = usum - Ua2; u_lds[2 * lane + 1] = up2 + a; v2 -= a; }
        if (used & 8) { const double a = usum - Ua3; u_lds[2 * lane + 2] = up3 + a; v3 -= a; }
        if (lane == 0) { p_lds[j1] = i; u_lds[i] = usum; }
        __syncthreads();
    }

    // out[b][k] = p[k+1] - 1 for the K real columns
    for (int j = lane; j < K_; j += 64)
        out[b * K_ + j] = p_lds[j + 1] - 1;
}

// ------------------------------------------------------------------- launcher
extern "C" void kernel_launch(void* const* d_in, const int* in_sizes, int n_in,
                              void* d_out, int out_size, void* d_ws, size_t ws_size,
                              hipStream_t stream) {
    const float* mp = (const float*)d_in[0];   // meta_points
    const float* mv = (const float*)d_in[1];   // meta_visibles
    /* d_in[2] covisibles: unused by reference */
    const float* gt = (const float*)d_in[3];   // gtpoints
    const float* gv = (const float*)d_in[4];   // gtvisibles
    int* out = (int*)d_out;                    // int32 assignment indices
    float* cost = (float*)d_ws;                // 16*256*128 fp32 = 2 MB

    dim3 gridA(B_, M_);
    cost_kernel<<<gridA, K_, 0, stream>>>(mp, mv, gt, gv, cost);
    match_kernel<<<B_, 64, 0, stream>>>(cost, out);
}